// Round 4
// baseline (1876.815 us; speedup 1.0000x reference)
//
#include <hip/hip_runtime.h>

#define HDIM 128
#define TTOK 8
#define NPG 1024

typedef unsigned short ushort;

__device__ __forceinline__ float bf2f(ushort u) {
    return __uint_as_float(((unsigned int)u) << 16);
}
__device__ __forceinline__ ushort f2bf(float f) {
    unsigned int x = __float_as_uint(f);
    return (ushort)((x + 0x7FFFu + ((x >> 16) & 1u)) >> 16);
}

// ================= counting sort of edges by dst =================

__global__ __launch_bounds__(256) void hist_kernel(const int* __restrict__ dst,
                                                   int* __restrict__ count, int E)
{
    int e = blockIdx.x * 256 + threadIdx.x;
    if (e < E) atomicAdd(&count[dst[e]], 1);
}

__global__ __launch_bounds__(256) void reduce256_kernel(const int* __restrict__ count,
                                                        int* __restrict__ blocksum)
{
    __shared__ int sm[256];
    int tid = threadIdx.x;
    sm[tid] = count[blockIdx.x * 256 + tid];
    __syncthreads();
    for (int s = 128; s; s >>= 1) {
        if (tid < s) sm[tid] += sm[tid + s];
        __syncthreads();
    }
    if (tid == 0) blocksum[blockIdx.x] = sm[0];
}

__global__ __launch_bounds__(512) void scan512_kernel(const int* __restrict__ blocksum,
                                                      int* __restrict__ blockoff)
{
    __shared__ int tmp[512];
    int tid = threadIdx.x;
    int v = blocksum[tid];
    tmp[tid] = v;
    __syncthreads();
    for (int off = 1; off < 512; off <<= 1) {
        int t = (tid >= off) ? tmp[tid - off] : 0;
        __syncthreads();
        tmp[tid] += t;
        __syncthreads();
    }
    blockoff[tid] = tmp[tid] - v;  // exclusive
}

__global__ __launch_bounds__(256) void scan_local_kernel(const int* __restrict__ count,
    const int* __restrict__ blockoff, int* __restrict__ starts,
    int* __restrict__ cursor, int N)
{
    __shared__ int tmp[256];
    int tid = threadIdx.x;
    int i = blockIdx.x * 256 + tid;
    int v = count[i];
    tmp[tid] = v;
    __syncthreads();
    for (int off = 1; off < 256; off <<= 1) {
        int t = (tid >= off) ? tmp[tid - off] : 0;
        __syncthreads();
        tmp[tid] += t;
        __syncthreads();
    }
    int excl = tmp[tid] - v + blockoff[blockIdx.x];
    starts[i] = excl;
    cursor[i] = excl;
    if (i == N - 1) starts[N] = excl + v;  // == E
}

__global__ __launch_bounds__(256) void sort_scatter_kernel(const int* __restrict__ src,
    const int* __restrict__ dst, int* __restrict__ cursor,
    int* __restrict__ ssrc, int E)
{
    int e = blockIdx.x * 256 + threadIdx.x;
    if (e >= E) return;
    int pos = atomicAdd(&cursor[dst[e]], 1);
    ssrc[pos] = src[e];
}

// ================= f32 -> bf16 convert =================
__global__ __launch_bounds__(256) void convert_kernel(const float* __restrict__ in,
                                                      ushort* __restrict__ outb, int n4)
{
    int i = blockIdx.x * 256 + threadIdx.x;
    if (i >= n4) return;
    float4 v = ((const float4*)in)[i];
    ushort4 o;
    o.x = f2bf(v.x); o.y = f2bf(v.y); o.z = f2bf(v.z); o.w = f2bf(v.w);
    ((ushort4*)outb)[i] = o;
}

// ================= fused GIN: XD[n] = bf16( (x[n]+sum_j x[src]) @ W + b [+ GF[n>>10]] ) =================
// 8 nodes per block, 32 lanes per node (4 columns per lane).
__global__ __launch_bounds__(256) void gather_lin_kernel(const ushort* __restrict__ XS,
    const int* __restrict__ ssrc, const int* __restrict__ starts,
    const int* __restrict__ count, const float* __restrict__ W,
    const float* __restrict__ bias, const float* __restrict__ GF,
    ushort* __restrict__ XD)
{
    __shared__ float xr[8][132];
    int tid = threadIdx.x;
    int g = tid >> 5, lane = tid & 31;
    int node = blockIdx.x * 8 + g;
    const int c = lane * 4;
    ushort4 sv = *(const ushort4*)(XS + (size_t)node * HDIM + c);
    float a0 = bf2f(sv.x), a1 = bf2f(sv.y), a2 = bf2f(sv.z), a3 = bf2f(sv.w);
    int s0 = starts[node], cn = count[node];
    for (int j0 = 0; j0 < cn; j0 += 32) {
        int myid = (j0 + lane < cn) ? ssrc[s0 + j0 + lane] : 0;
        int m = min(32, cn - j0);
        int j = 0;
        for (; j + 1 < m; j += 2) {
            int sa = __shfl(myid, j, 32);
            int sb = __shfl(myid, j + 1, 32);
            ushort4 va = *(const ushort4*)(XS + (size_t)sa * HDIM + c);
            ushort4 vb = *(const ushort4*)(XS + (size_t)sb * HDIM + c);
            a0 += bf2f(va.x) + bf2f(vb.x);
            a1 += bf2f(va.y) + bf2f(vb.y);
            a2 += bf2f(va.z) + bf2f(vb.z);
            a3 += bf2f(va.w) + bf2f(vb.w);
        }
        if (j < m) {
            int sa = __shfl(myid, j, 32);
            ushort4 va = *(const ushort4*)(XS + (size_t)sa * HDIM + c);
            a0 += bf2f(va.x); a1 += bf2f(va.y); a2 += bf2f(va.z); a3 += bf2f(va.w);
        }
    }
    xr[g][c + 0] = a0; xr[g][c + 1] = a1; xr[g][c + 2] = a2; xr[g][c + 3] = a3;
    __syncthreads();
    // matmul: out cols [c, c+4)
    float4 acc = *(const float4*)(bias + c);
    if (GF) {
        float4 gf = *(const float4*)(GF + (size_t)(node >> 10) * HDIM + c);
        acc.x += gf.x; acc.y += gf.y; acc.z += gf.z; acc.w += gf.w;
    }
    #pragma unroll 4
    for (int k = 0; k < 128; ++k) {
        float xv = xr[g][k];
        float4 w4 = *(const float4*)(W + (size_t)k * HDIM + c);
        acc.x += xv * w4.x; acc.y += xv * w4.y;
        acc.z += xv * w4.z; acc.w += xv * w4.w;
    }
    ushort4 o;
    o.x = f2bf(acc.x); o.y = f2bf(acc.y); o.z = f2bf(acc.z); o.w = f2bf(acc.w);
    *(ushort4*)(XD + (size_t)node * HDIM + c) = o;
}

// ================= Y = X1 @ W + b (f32, small; used for attn output proj) =================
__global__ __launch_bounds__(256) void lin128_kernel(const float* __restrict__ X1,
    const float* __restrict__ W, const float* __restrict__ bias,
    float* __restrict__ Y)
{
    __shared__ float Wl[128 * 128];
    __shared__ float xr[32][128];
    int tid = threadIdx.x;
    for (int i = tid; i < 4096; i += 256)
        ((float4*)Wl)[i] = ((const float4*)W)[i];
    size_t r0 = (size_t)blockIdx.x * 32;
    for (int i = tid; i < 32 * 32; i += 256) {
        int r = i >> 5, c4 = i & 31;
        *(float4*)&xr[r][c4 * 4] = *(const float4*)(X1 + (r0 + r) * HDIM + c4 * 4);
    }
    __syncthreads();
    int cg = tid & 31, rg = tid >> 5;
    int c0 = cg * 4, rb = rg * 4;
    float4 bv = *(const float4*)(bias + c0);
    float4 a0 = bv, a1 = bv, a2 = bv, a3 = bv;
    for (int k = 0; k < 128; ++k) {
        float4 w = *(const float4*)&Wl[k * 128 + c0];
        float x0 = xr[rb + 0][k], x1 = xr[rb + 1][k], x2 = xr[rb + 2][k], x3 = xr[rb + 3][k];
        a0.x += x0 * w.x; a0.y += x0 * w.y; a0.z += x0 * w.z; a0.w += x0 * w.w;
        a1.x += x1 * w.x; a1.y += x1 * w.y; a1.z += x1 * w.z; a1.w += x1 * w.w;
        a2.x += x2 * w.x; a2.y += x2 * w.y; a2.z += x2 * w.z; a2.w += x2 * w.w;
        a3.x += x3 * w.x; a3.y += x3 * w.y; a3.z += x3 * w.z; a3.w += x3 * w.w;
    }
    *(float4*)(Y + (r0 + rb + 0) * HDIM + c0) = a0;
    *(float4*)(Y + (r0 + rb + 1) * HDIM + c0) = a1;
    *(float4*)(Y + (r0 + rb + 2) * HDIM + c0) = a2;
    *(float4*)(Y + (r0 + rb + 3) * HDIM + c0) = a3;
}

// ================= attention prep: P[h][t][:] = Wk_h @ q[t,h] / sqrt(32) =================
__global__ __launch_bounds__(256) void attn_prep_kernel(const float* __restrict__ vt,
    const float* __restrict__ qkv_w, const float* __restrict__ qkv_b, float* __restrict__ P)
{
    __shared__ float vtl[TTOK][HDIM];
    __shared__ float q[TTOK][HDIM];
    int tid = threadIdx.x;
    for (int i = tid; i < TTOK * HDIM; i += 256) vtl[i >> 7][i & 127] = vt[i];
    __syncthreads();
    for (int i = tid; i < TTOK * HDIM; i += 256) {
        int t = i >> 7, j = i & 127;
        float acc = qkv_b[j];
        for (int c = 0; c < 128; ++c) acc += vtl[t][c] * qkv_w[c * 384 + j];
        q[t][j] = acc;
    }
    __syncthreads();
    const float scale = 0.17677669529663687f; // 1/sqrt(32)
    for (int i = tid; i < 4 * TTOK * HDIM; i += 256) {
        int h = i >> 10, t = (i >> 7) & 7, cc = i & 127;
        float acc = 0.f;
        for (int d = 0; d < 32; ++d)
            acc += qkv_w[cc * 384 + 128 + h * 32 + d] * q[t][h * 32 + d];
        P[i] = acc * scale;
    }
}

// ================= fused attention per (graph, head), bf16 X =================
__global__ __launch_bounds__(256) void attn_main_kernel(const ushort* __restrict__ X,
    const float* __restrict__ P, const float* __restrict__ qkv_w,
    const float* __restrict__ qkv_b, float* __restrict__ O)
{
    __shared__ float sc[TTOK][NPG];   // 32 KB scores
    __shared__ float ph[TTOK][132];
    __shared__ float xt[32][132];
    __shared__ float rr[TTOK][HDIM];
    __shared__ float red[16];
    int b = blockIdx.x >> 2;
    int h = blockIdx.x & 3;
    int tid = threadIdx.x;
    for (int i = tid; i < TTOK * HDIM; i += 256) ph[i >> 7][i & 127] = P[h * 1024 + i];
    __syncthreads();
    const ushort* xg = X + (size_t)b * NPG * HDIM;
    for (int n0 = 0; n0 < NPG; n0 += 32) {
        for (int i = tid; i < 32 * 16; i += 256) {
            int n = i >> 4, c8 = (i & 15) * 8;
            ushort4 va = *(const ushort4*)(xg + (size_t)(n0 + n) * HDIM + c8);
            ushort4 vb = *(const ushort4*)(xg + (size_t)(n0 + n) * HDIM + c8 + 4);
            float4 fa = {bf2f(va.x), bf2f(va.y), bf2f(va.z), bf2f(va.w)};
            float4 fb = {bf2f(vb.x), bf2f(vb.y), bf2f(vb.z), bf2f(vb.w)};
            *(float4*)&xt[n][c8] = fa;
            *(float4*)&xt[n][c8 + 4] = fb;
        }
        __syncthreads();
        int n = tid >> 3, t = tid & 7;
        float acc = 0.f;
        for (int k = 0; k < 128; k += 4) {
            float4 xv = *(const float4*)&xt[n][k];
            float4 pv = *(const float4*)&ph[t][k];
            acc += xv.x * pv.x + xv.y * pv.y + xv.z * pv.z + xv.w * pv.w;
        }
        sc[t][n0 + n] = acc;
        __syncthreads();
    }
    for (int t = 0; t < TTOK; ++t) {
        float m = -1e30f;
        for (int n = tid; n < NPG; n += 256) m = fmaxf(m, sc[t][n]);
        for (int off = 32; off; off >>= 1) m = fmaxf(m, __shfl_down(m, off));
        if ((tid & 63) == 0) red[tid >> 6] = m;
        __syncthreads();
        m = fmaxf(fmaxf(red[0], red[1]), fmaxf(red[2], red[3]));
        float s = 0.f;
        for (int n = tid; n < NPG; n += 256) {
            float e = __expf(sc[t][n] - m);
            sc[t][n] = e;
            s += e;
        }
        for (int off = 32; off; off >>= 1) s += __shfl_down(s, off);
        if ((tid & 63) == 0) red[4 + (tid >> 6)] = s;
        __syncthreads();
        s = red[4] + red[5] + red[6] + red[7];
        float inv = 1.f / s;
        for (int n = tid; n < NPG; n += 256) sc[t][n] *= inv;
        __syncthreads();
    }
    {
        int t = tid >> 5, c4 = (tid & 31) * 4;
        float4 acc = {0.f, 0.f, 0.f, 0.f};
        for (int n = 0; n < NPG; ++n) {
            float w = sc[t][n];
            ushort4 v = *(const ushort4*)(xg + (size_t)n * HDIM + c4);
            acc.x += w * bf2f(v.x); acc.y += w * bf2f(v.y);
            acc.z += w * bf2f(v.z); acc.w += w * bf2f(v.w);
        }
        *(float4*)&rr[t][c4] = acc;
    }
    __syncthreads();
    {
        int t = tid >> 5, d = tid & 31;
        float acc = qkv_b[256 + h * 32 + d];
        for (int c = 0; c < 128; ++c)
            acc += rr[t][c] * qkv_w[c * 384 + 256 + h * 32 + d];
        O[((size_t)b * TTOK + t) * HDIM + h * 32 + d] = acc;
    }
}

// ================= mamba: one block per graph; GF[b][:] = mean_t output =================
__global__ __launch_bounds__(256) void mamba_kernel(const float* __restrict__ TOKp,
    const float* __restrict__ in_w, const float* __restrict__ conv_w,
    const float* __restrict__ conv_b, const float* __restrict__ x_w,
    const float* __restrict__ dt_w, const float* __restrict__ dt_b,
    const float* __restrict__ A_log, const float* __restrict__ Dp,
    const float* __restrict__ out_w, const float* __restrict__ norm_w,
    const float* __restrict__ normf_w, float* __restrict__ GF)
{
    constexpr int I = 256, S = 16;
    __shared__ float tok[TTOK][HDIM];
    __shared__ float hn[TTOK][HDIM];
    __shared__ float uu[TTOK][I];
    __shared__ float gg[TTOK][I];
    __shared__ float dtl[TTOK][I];
    __shared__ float ssm[TTOK][40];
    __shared__ float yy[TTOK][I];
    int b = blockIdx.x, tid = threadIdx.x;
    for (int i = tid; i < TTOK * HDIM; i += 256) tok[i >> 7][i & 127] = TOKp[(size_t)b * TTOK * HDIM + i];
    __syncthreads();
    {
        int t = tid >> 5, lane = tid & 31;
        float s = 0.f;
        for (int c = lane; c < HDIM; c += 32) { float v = tok[t][c]; s += v * v; }
        for (int off = 16; off; off >>= 1) s += __shfl_down(s, off, 32);
        s = __shfl(s, 0, 32);
        float r = rsqrtf(s / HDIM + 1e-5f);
        for (int c = lane; c < HDIM; c += 32) hn[t][c] = tok[t][c] * r * norm_w[c];
    }
    __syncthreads();
    for (int it = 0; it < 16; ++it) {
        int idx = it * 256 + tid;
        int t = idx >> 9, j = idx & 511;
        float acc = 0.f;
        for (int c = 0; c < 128; ++c) acc += hn[t][c] * in_w[c * 512 + j];
        if (j < 256) uu[t][j] = acc; else gg[t][j - 256] = acc;
    }
    __syncthreads();
    {
        int i = tid;
        float cw0 = conv_w[i * 4 + 0], cw1 = conv_w[i * 4 + 1];
        float cw2 = conv_w[i * 4 + 2], cw3 = conv_w[i * 4 + 3];
        float cb = conv_b[i];
        float uv[TTOK];
        for (int t = 0; t < TTOK; ++t) uv[t] = uu[t][i];
        for (int t = 0; t < TTOK; ++t) {
            float a = cw3 * uv[t] + cb;
            if (t >= 1) a += cw2 * uv[t - 1];
            if (t >= 2) a += cw1 * uv[t - 2];
            if (t >= 3) a += cw0 * uv[t - 3];
            float sg = 1.f / (1.f + __expf(-a));
            uu[t][i] = a * sg;
        }
    }
    __syncthreads();
    for (int idx = tid; idx < TTOK * 40; idx += 256) {
        int t = idx / 40, j = idx % 40;
        float acc = 0.f;
        for (int c = 0; c < 256; ++c) acc += uu[t][c] * x_w[c * 40 + j];
        ssm[t][j] = acc;
    }
    __syncthreads();
    for (int idx = tid; idx < TTOK * I; idx += 256) {
        int t = idx >> 8, i = idx & 255;
        float acc = dt_b[i];
        for (int r = 0; r < 8; ++r) acc += ssm[t][r] * dt_w[r * 256 + i];
        dtl[t][i] = (acc > 20.f) ? acc : log1pf(__expf(acc));
    }
    __syncthreads();
    {
        int i = tid;
        float a[S], st[S];
        for (int s = 0; s < S; ++s) { a[s] = -__expf(A_log[i * S + s]); st[s] = 0.f; }
        float Di = Dp[i];
        for (int t = 0; t < TTOK; ++t) {
            float d = dtl[t][i];
            float ut = uu[t][i];
            float y = 0.f;
            for (int s = 0; s < S; ++s) {
                float dA = __expf(d * a[s]);
                st[s] = dA * st[s] + d * ssm[t][8 + s] * ut;
                y += st[s] * ssm[t][24 + s];
            }
            y += ut * Di;
            float g = gg[t][i];
            float sg = 1.f / (1.f + __expf(-g));
            yy[t][i] = y * g * sg;
        }
    }
    __syncthreads();
    for (int idx = tid; idx < TTOK * HDIM; idx += 256) {
        int t = idx >> 7, c = idx & 127;
        float acc = tok[t][c];
        for (int i = 0; i < 256; ++i) acc += yy[t][i] * out_w[i * 128 + c];
        hn[t][c] = acc;
    }
    __syncthreads();
    {
        int t = tid >> 5, lane = tid & 31;
        float s = 0.f;
        for (int c = lane; c < HDIM; c += 32) { float v = hn[t][c]; s += v * v; }
        for (int off = 16; off; off >>= 1) s += __shfl_down(s, off, 32);
        s = __shfl(s, 0, 32);
        float r = rsqrtf(s / HDIM + 1e-5f);
        for (int c = lane; c < HDIM; c += 32) hn[t][c] = hn[t][c] * r * normf_w[c];
    }
    __syncthreads();
    for (int c = tid; c < HDIM; c += 256) {
        float s = 0.f;
        for (int t = 0; t < TTOK; ++t) s += hn[t][c];
        GF[(size_t)b * HDIM + c] = s * (1.f / TTOK);
    }
}

// ================= final GIN + segment_sum: partial sums, 32 blocks/graph, bf16 X =================
__global__ __launch_bounds__(256) void final_partial_kernel(const ushort* __restrict__ X,
    const int* __restrict__ ssrc, const int* __restrict__ starts,
    float* __restrict__ PS)
{
    __shared__ float part[8][HDIM];
    int b = blockIdx.x >> 5;        // graph
    int j = blockIdx.x & 31;        // slice within graph
    int tid = threadIdx.x;
    int g = tid >> 5, lane = tid & 31;
    const int c = lane * 4;
    float a0 = 0.f, a1 = 0.f, a2 = 0.f, a3 = 0.f;
    {
        int nb = j * 32 + g * 4;
        for (int n = nb; n < nb + 4; ++n) {
            ushort4 v = *(const ushort4*)(X + ((size_t)b * NPG + n) * HDIM + c);
            a0 += bf2f(v.x); a1 += bf2f(v.y); a2 += bf2f(v.z); a3 += bf2f(v.w);
        }
    }
    {
        int e0 = starts[b * NPG], e1 = starts[(b + 1) * NPG];
        int tot = e1 - e0;
        int gi = j * 8 + g;                      // 0..255
        int per = (tot + 255) >> 8;
        int cs = e0 + gi * per;
        int ce = min(cs + per, e1);
        for (int j0 = cs; j0 < ce; j0 += 32) {
            int myid = (j0 + lane < ce) ? ssrc[j0 + lane] : 0;
            int m = min(32, ce - j0);
            for (int jj = 0; jj < m; ++jj) {
                int sa = __shfl(myid, jj, 32);
                ushort4 v = *(const ushort4*)(X + (size_t)sa * HDIM + c);
                a0 += bf2f(v.x); a1 += bf2f(v.y); a2 += bf2f(v.z); a3 += bf2f(v.w);
            }
        }
    }
    part[g][c + 0] = a0; part[g][c + 1] = a1; part[g][c + 2] = a2; part[g][c + 3] = a3;
    __syncthreads();
    if (tid < HDIM) {
        float s = 0.f;
        for (int gg = 0; gg < 8; ++gg) s += part[gg][tid];
        atomicAdd(&PS[(size_t)b * HDIM + tid], s);
    }
}

__global__ __launch_bounds__(128) void final_mm_kernel(const float* __restrict__ PS,
    const float* __restrict__ w_out, const float* __restrict__ b_out,
    float* __restrict__ out)
{
    __shared__ float Sm[HDIM];
    int b = blockIdx.x, tid = threadIdx.x;
    Sm[tid] = PS[(size_t)b * HDIM + tid];
    __syncthreads();
    float acc = 1024.f * b_out[tid];
    for (int k = 0; k < 128; ++k) acc += Sm[k] * w_out[k * 128 + tid];
    out[(size_t)b * HDIM + tid] = acc;
}

extern "C" void kernel_launch(void* const* d_in, const int* in_sizes, int n_in,
                              void* d_out, int out_size, void* d_ws, size_t ws_size,
                              hipStream_t stream)
{
    const int N = in_sizes[0] / HDIM;      // 131072
    const int E = in_sizes[1] / 2;         // 2097152
    const int B = N >> 10;                 // 128 graphs

    const float* x_in  = (const float*)d_in[0];
    const int*   src   = (const int*)d_in[1];
    const int*   dst   = src + E;
    const float* w_in  = (const float*)d_in[5];
    const float* b_in  = (const float*)d_in[6];
    const float* gin_w = (const float*)d_in[7];
    const float* gin_b = (const float*)d_in[8];
    const float* vt    = (const float*)d_in[9];
    const float* qkv_w = (const float*)d_in[10];
    const float* qkv_b = (const float*)d_in[11];
    const float* ao_w  = (const float*)d_in[12];
    const float* ao_b  = (const float*)d_in[13];
    const float* m_in_w   = (const float*)d_in[14];
    const float* m_conv_w = (const float*)d_in[15];
    const float* m_conv_b = (const float*)d_in[16];
    const float* m_x_w    = (const float*)d_in[17];
    const float* m_dt_w   = (const float*)d_in[18];
    const float* m_dt_b   = (const float*)d_in[19];
    const float* m_A_log  = (const float*)d_in[20];
    const float* m_D      = (const float*)d_in[21];
    const float* m_out_w  = (const float*)d_in[22];
    const float* m_norm_w = (const float*)d_in[23];
    const float* m_normf_w= (const float*)d_in[24];
    const float* w_out = (const float*)d_in[25];
    const float* b_out = (const float*)d_in[26];
    float* out = (float*)d_out;

    float* TOK = (float*)d_ws;                    // B*8*128
    float* O   = TOK + (size_t)B * TTOK * HDIM;   // B*8*128
    float* GF  = O + (size_t)B * TTOK * HDIM;     // B*128
    float* P   = GF + (size_t)B * HDIM;           // 4*8*128
    float* PS  = P + 4 * TTOK * HDIM;             // B*128
    int* count    = (int*)(PS + (size_t)B * HDIM);// N
    int* starts   = count + N;                    // N+1 (padded to N+8)
    int* cursor   = starts + N + 8;               // N
    int* blocksum = cursor + N;                   // 512
    int* blockoff = blocksum + 512;               // 512
    int* ssrc     = blockoff + 512;               // E
    ushort* XB0 = (ushort*)(ssrc + E);            // N*128 bf16
    ushort* XB1 = XB0 + (size_t)N * HDIM;         // N*128 bf16
    ushort* XB2 = XB1 + (size_t)N * HDIM;         // N*128 bf16

    const int EB = (E + 255) / 256;   // 8192
    const int NB = N / 256;           // 512

    // ---- counting sort of edges by dst (once, reused by all 4 GINs) ----
    hipMemsetAsync(count, 0, (size_t)N * sizeof(int), stream);
    hist_kernel<<<EB, 256, 0, stream>>>(dst, count, E);
    reduce256_kernel<<<NB, 256, 0, stream>>>(count, blocksum);
    scan512_kernel<<<1, 512, 0, stream>>>(blocksum, blockoff);
    scan_local_kernel<<<NB, 256, 0, stream>>>(count, blockoff, starts, cursor, N);
    sort_scatter_kernel<<<EB, 256, 0, stream>>>(src, dst, cursor, ssrc, E);

    // ---- convert input to bf16, then input GIN fused: XB1 = (x+agg(x))@w_in + b_in ----
    convert_kernel<<<(N * 32 + 255) / 256, 256, 0, stream>>>(x_in, XB0, N * 32);
    gather_lin_kernel<<<N / 8, 256, 0, stream>>>(XB0, ssrc, starts, count,
                                                 w_in, b_in, nullptr, XB1);

    ushort* Xcur = XB1;
    ushort* Xnext = XB2;
    for (int l = 0; l < 2; ++l) {
        // attention pool on Xcur -> O -> TOK -> mamba -> GF
        attn_prep_kernel<<<1, 256, 0, stream>>>(vt + (size_t)l * TTOK * HDIM,
                                                qkv_w + (size_t)l * 128 * 384,
                                                qkv_b + (size_t)l * 384, P);
        attn_main_kernel<<<B * 4, 256, 0, stream>>>(Xcur, P,
                                                    qkv_w + (size_t)l * 128 * 384,
                                                    qkv_b + (size_t)l * 384, O);
        lin128_kernel<<<(B * TTOK) / 32, 256, 0, stream>>>(O, ao_w + (size_t)l * 128 * 128,
                                                           ao_b + (size_t)l * 128, TOK);
        mamba_kernel<<<B, 256, 0, stream>>>(TOK, m_in_w, m_conv_w, m_conv_b, m_x_w,
                                            m_dt_w, m_dt_b, m_A_log, m_D, m_out_w,
                                            m_norm_w, m_normf_w, GF);
        // Xnext = (Xcur + agg(Xcur)) @ gin_w + gin_b + GF[batch]   (fully fused)
        gather_lin_kernel<<<N / 8, 256, 0, stream>>>(Xcur, ssrc, starts, count,
                                                     gin_w + (size_t)l * 128 * 128,
                                                     gin_b + (size_t)l * 128, GF, Xnext);
        ushort* t = Xcur; Xcur = Xnext; Xnext = t;
    }

    // ---- final GIN + segment_sum: partials + tiny matmul ----
    hipMemsetAsync(PS, 0, (size_t)B * HDIM * sizeof(float), stream);
    final_partial_kernel<<<B * 32, 256, 0, stream>>>(Xcur, ssrc, starts, PS);
    final_mm_kernel<<<B, 128, 0, stream>>>(PS, w_out, b_out, out);

    (void)n_in; (void)out_size; (void)ws_size;
}

// Round 5
// 1588.738 us; speedup vs baseline: 1.1813x; 1.1813x over previous
//
#include <hip/hip_runtime.h>

#define HDIM 128
#define TTOK 8
#define NPG 1024

typedef unsigned short ushort;
typedef unsigned int uint;

__device__ __forceinline__ float bf2f(ushort u) {
    return __uint_as_float(((unsigned int)u) << 16);
}
__device__ __forceinline__ ushort f2bf(float f) {
    unsigned int x = __float_as_uint(f);
    return (ushort)((x + 0x7FFFu + ((x >> 16) & 1u)) >> 16);
}
__device__ __forceinline__ float blo(uint u) { return __uint_as_float(u << 16); }
__device__ __forceinline__ float bhi(uint u) { return __uint_as_float(u & 0xFFFF0000u); }
__device__ __forceinline__ uint pk(float a, float b) {
    return (uint)f2bf(a) | ((uint)f2bf(b) << 16);
}

// ================= counting sort of edges by dst =================

__global__ __launch_bounds__(256) void hist_kernel(const int* __restrict__ dst,
                                                   int* __restrict__ count, int E)
{
    int e = blockIdx.x * 256 + threadIdx.x;
    if (e < E) atomicAdd(&count[dst[e]], 1);
}

__global__ __launch_bounds__(256) void reduce256_kernel(const int* __restrict__ count,
                                                        int* __restrict__ blocksum)
{
    __shared__ int sm[256];
    int tid = threadIdx.x;
    sm[tid] = count[blockIdx.x * 256 + tid];
    __syncthreads();
    for (int s = 128; s; s >>= 1) {
        if (tid < s) sm[tid] += sm[tid + s];
        __syncthreads();
    }
    if (tid == 0) blocksum[blockIdx.x] = sm[0];
}

__global__ __launch_bounds__(512) void scan512_kernel(const int* __restrict__ blocksum,
                                                      int* __restrict__ blockoff)
{
    __shared__ int tmp[512];
    int tid = threadIdx.x;
    int v = blocksum[tid];
    tmp[tid] = v;
    __syncthreads();
    for (int off = 1; off < 512; off <<= 1) {
        int t = (tid >= off) ? tmp[tid - off] : 0;
        __syncthreads();
        tmp[tid] += t;
        __syncthreads();
    }
    blockoff[tid] = tmp[tid] - v;  // exclusive
}

__global__ __launch_bounds__(256) void scan_local_kernel(const int* __restrict__ count,
    const int* __restrict__ blockoff, int* __restrict__ starts,
    int* __restrict__ cursor, int N)
{
    __shared__ int tmp[256];
    int tid = threadIdx.x;
    int i = blockIdx.x * 256 + tid;
    int v = count[i];
    tmp[tid] = v;
    __syncthreads();
    for (int off = 1; off < 256; off <<= 1) {
        int t = (tid >= off) ? tmp[tid - off] : 0;
        __syncthreads();
        tmp[tid] += t;
        __syncthreads();
    }
    int excl = tmp[tid] - v + blockoff[blockIdx.x];
    starts[i] = excl;
    cursor[i] = excl;
    if (i == N - 1) starts[N] = excl + v;  // == E
}

__global__ __launch_bounds__(256) void sort_scatter_kernel(const int* __restrict__ src,
    const int* __restrict__ dst, int* __restrict__ cursor,
    int* __restrict__ ssrc, int E)
{
    int e = blockIdx.x * 256 + threadIdx.x;
    if (e >= E) return;
    int pos = atomicAdd(&cursor[dst[e]], 1);
    ssrc[pos] = src[e];
}

// ================= f32 -> bf16 convert =================
__global__ __launch_bounds__(256) void convert_kernel(const float* __restrict__ in,
                                                      ushort* __restrict__ outb, int n4)
{
    int i = blockIdx.x * 256 + threadIdx.x;
    if (i >= n4) return;
    float4 v = ((const float4*)in)[i];
    uint2 o;
    o.x = pk(v.x, v.y); o.y = pk(v.z, v.w);
    ((uint2*)outb)[i] = o;
}

// ================= gather: AGG[n] = x[n] + sum_{e: dst=n} x[src[e]]  (bf16 in/out) =================
// 16 nodes per block, 16 lanes per node, uint4 = 8 bf16 per lane.
__global__ __launch_bounds__(256) void gather_kernel(const ushort* __restrict__ XS,
    const int* __restrict__ ssrc, const int* __restrict__ starts,
    const int* __restrict__ count, ushort* __restrict__ AGG)
{
    int tid = threadIdx.x;
    int g = tid >> 4, lane = tid & 15;
    int node = blockIdx.x * 16 + g;
    uint4 sv = *((const uint4*)(XS + (size_t)node * HDIM) + lane);
    float a0 = blo(sv.x), a1 = bhi(sv.x), a2 = blo(sv.y), a3 = bhi(sv.y);
    float a4 = blo(sv.z), a5 = bhi(sv.z), a6 = blo(sv.w), a7 = bhi(sv.w);
    int s0 = starts[node], cn = count[node];
    for (int j0 = 0; j0 < cn; j0 += 16) {
        int myid = (j0 + lane < cn) ? ssrc[s0 + j0 + lane] : 0;
        int m = min(16, cn - j0);
        int j = 0;
        for (; j + 1 < m; j += 2) {
            int sa = __shfl(myid, j, 16);
            int sb = __shfl(myid, j + 1, 16);
            uint4 ua = *((const uint4*)(XS + (size_t)sa * HDIM) + lane);
            uint4 ub = *((const uint4*)(XS + (size_t)sb * HDIM) + lane);
            a0 += blo(ua.x) + blo(ub.x); a1 += bhi(ua.x) + bhi(ub.x);
            a2 += blo(ua.y) + blo(ub.y); a3 += bhi(ua.y) + bhi(ub.y);
            a4 += blo(ua.z) + blo(ub.z); a5 += bhi(ua.z) + bhi(ub.z);
            a6 += blo(ua.w) + blo(ub.w); a7 += bhi(ua.w) + bhi(ub.w);
        }
        if (j < m) {
            int sa = __shfl(myid, j, 16);
            uint4 ua = *((const uint4*)(XS + (size_t)sa * HDIM) + lane);
            a0 += blo(ua.x); a1 += bhi(ua.x);
            a2 += blo(ua.y); a3 += bhi(ua.y);
            a4 += blo(ua.z); a5 += bhi(ua.z);
            a6 += blo(ua.w); a7 += bhi(ua.w);
        }
    }
    uint4 o;
    o.x = pk(a0, a1); o.y = pk(a2, a3); o.z = pk(a4, a5); o.w = pk(a6, a7);
    *((uint4*)(AGG + (size_t)node * HDIM) + lane) = o;
}

// ================= lin (bf16 in/out): XD = XS @ W + b [+ GF[row>>10]] =================
// 32 rows per block, W f32 staged in LDS, 4x4 register micro-tile.
__global__ __launch_bounds__(256) void lin128b_kernel(const ushort* __restrict__ XS,
    const float* __restrict__ W, const float* __restrict__ bias,
    const float* __restrict__ GF, ushort* __restrict__ XD)
{
    __shared__ float Wl[128 * 128];   // 64 KB
    __shared__ float xr[32][128];     // 16 KB
    int tid = threadIdx.x;
    for (int i = tid; i < 4096; i += 256)
        ((float4*)Wl)[i] = ((const float4*)W)[i];
    size_t r0 = (size_t)blockIdx.x * 32;
    for (int i = tid; i < 32 * 16; i += 256) {
        int r = i >> 4, cc = i & 15;
        uint4 u = *((const uint4*)(XS + (r0 + r) * HDIM) + cc);
        float4 f0 = {blo(u.x), bhi(u.x), blo(u.y), bhi(u.y)};
        float4 f1 = {blo(u.z), bhi(u.z), blo(u.w), bhi(u.w)};
        *(float4*)&xr[r][cc * 8] = f0;
        *(float4*)&xr[r][cc * 8 + 4] = f1;
    }
    __syncthreads();
    int cg = tid & 31, rg = tid >> 5;
    int c0 = cg * 4, rb = rg * 4;
    float4 bv = *(const float4*)(bias + c0);
    if (GF) {
        int b = (int)((r0 + rb) >> 10);  // 32-row block never crosses a graph boundary
        float4 gfv = *(const float4*)(GF + (size_t)b * HDIM + c0);
        bv.x += gfv.x; bv.y += gfv.y; bv.z += gfv.z; bv.w += gfv.w;
    }
    float4 a0 = bv, a1 = bv, a2 = bv, a3 = bv;
    for (int k = 0; k < 128; ++k) {
        float4 w = *(const float4*)&Wl[k * 128 + c0];
        float x0 = xr[rb + 0][k], x1 = xr[rb + 1][k], x2 = xr[rb + 2][k], x3 = xr[rb + 3][k];
        a0.x += x0 * w.x; a0.y += x0 * w.y; a0.z += x0 * w.z; a0.w += x0 * w.w;
        a1.x += x1 * w.x; a1.y += x1 * w.y; a1.z += x1 * w.z; a1.w += x1 * w.w;
        a2.x += x2 * w.x; a2.y += x2 * w.y; a2.z += x2 * w.z; a2.w += x2 * w.w;
        a3.x += x3 * w.x; a3.y += x3 * w.y; a3.z += x3 * w.z; a3.w += x3 * w.w;
    }
    uint2 o0 = {pk(a0.x, a0.y), pk(a0.z, a0.w)};
    uint2 o1 = {pk(a1.x, a1.y), pk(a1.z, a1.w)};
    uint2 o2 = {pk(a2.x, a2.y), pk(a2.z, a2.w)};
    uint2 o3 = {pk(a3.x, a3.y), pk(a3.z, a3.w)};
    *(uint2*)(XD + (r0 + rb + 0) * HDIM + c0) = o0;
    *(uint2*)(XD + (r0 + rb + 1) * HDIM + c0) = o1;
    *(uint2*)(XD + (r0 + rb + 2) * HDIM + c0) = o2;
    *(uint2*)(XD + (r0 + rb + 3) * HDIM + c0) = o3;
}

// ================= Y = X1 @ W + b (f32; attn output proj -> TOK) =================
__global__ __launch_bounds__(256) void lin128_kernel(const float* __restrict__ X1,
    const float* __restrict__ W, const float* __restrict__ bias,
    float* __restrict__ Y)
{
    __shared__ float Wl[128 * 128];
    __shared__ float xr[32][128];
    int tid = threadIdx.x;
    for (int i = tid; i < 4096; i += 256)
        ((float4*)Wl)[i] = ((const float4*)W)[i];
    size_t r0 = (size_t)blockIdx.x * 32;
    for (int i = tid; i < 32 * 32; i += 256) {
        int r = i >> 5, c4 = i & 31;
        *(float4*)&xr[r][c4 * 4] = *(const float4*)(X1 + (r0 + r) * HDIM + c4 * 4);
    }
    __syncthreads();
    int cg = tid & 31, rg = tid >> 5;
    int c0 = cg * 4, rb = rg * 4;
    float4 bv = *(const float4*)(bias + c0);
    float4 a0 = bv, a1 = bv, a2 = bv, a3 = bv;
    for (int k = 0; k < 128; ++k) {
        float4 w = *(const float4*)&Wl[k * 128 + c0];
        float x0 = xr[rb + 0][k], x1 = xr[rb + 1][k], x2 = xr[rb + 2][k], x3 = xr[rb + 3][k];
        a0.x += x0 * w.x; a0.y += x0 * w.y; a0.z += x0 * w.z; a0.w += x0 * w.w;
        a1.x += x1 * w.x; a1.y += x1 * w.y; a1.z += x1 * w.z; a1.w += x1 * w.w;
        a2.x += x2 * w.x; a2.y += x2 * w.y; a2.z += x2 * w.z; a2.w += x2 * w.w;
        a3.x += x3 * w.x; a3.y += x3 * w.y; a3.z += x3 * w.z; a3.w += x3 * w.w;
    }
    *(float4*)(Y + (r0 + rb + 0) * HDIM + c0) = a0;
    *(float4*)(Y + (r0 + rb + 1) * HDIM + c0) = a1;
    *(float4*)(Y + (r0 + rb + 2) * HDIM + c0) = a2;
    *(float4*)(Y + (r0 + rb + 3) * HDIM + c0) = a3;
}

// ================= attention prep: P[h][t][:] = Wk_h @ q[t,h] / sqrt(32) =================
__global__ __launch_bounds__(256) void attn_prep_kernel(const float* __restrict__ vt,
    const float* __restrict__ qkv_w, const float* __restrict__ qkv_b, float* __restrict__ P)
{
    __shared__ float vtl[TTOK][HDIM];
    __shared__ float q[TTOK][HDIM];
    int tid = threadIdx.x;
    for (int i = tid; i < TTOK * HDIM; i += 256) vtl[i >> 7][i & 127] = vt[i];
    __syncthreads();
    for (int i = tid; i < TTOK * HDIM; i += 256) {
        int t = i >> 7, j = i & 127;
        float acc = qkv_b[j];
        for (int c = 0; c < 128; ++c) acc += vtl[t][c] * qkv_w[c * 384 + j];
        q[t][j] = acc;
    }
    __syncthreads();
    const float scale = 0.17677669529663687f; // 1/sqrt(32)
    for (int i = tid; i < 4 * TTOK * HDIM; i += 256) {
        int h = i >> 10, t = (i >> 7) & 7, cc = i & 127;
        float acc = 0.f;
        for (int d = 0; d < 32; ++d)
            acc += qkv_w[cc * 384 + 128 + h * 32 + d] * q[t][h * 32 + d];
        P[i] = acc * scale;
    }
}

// ================= fused attention per (graph, head), bf16 X =================
__global__ __launch_bounds__(256) void attn_main_kernel(const ushort* __restrict__ X,
    const float* __restrict__ P, const float* __restrict__ qkv_w,
    const float* __restrict__ qkv_b, float* __restrict__ O)
{
    __shared__ float sc[TTOK][NPG];   // 32 KB scores
    __shared__ float ph[TTOK][132];
    __shared__ float xt[32][132];
    __shared__ float rr[TTOK][HDIM];
    __shared__ float red[16];
    int b = blockIdx.x >> 2;
    int h = blockIdx.x & 3;
    int tid = threadIdx.x;
    for (int i = tid; i < TTOK * HDIM; i += 256) ph[i >> 7][i & 127] = P[h * 1024 + i];
    __syncthreads();
    const ushort* xg = X + (size_t)b * NPG * HDIM;
    for (int n0 = 0; n0 < NPG; n0 += 32) {
        for (int i = tid; i < 32 * 16; i += 256) {
            int n = i >> 4, cc = i & 15;
            uint4 u = *((const uint4*)(xg + (size_t)(n0 + n) * HDIM) + cc);
            float4 f0 = {blo(u.x), bhi(u.x), blo(u.y), bhi(u.y)};
            float4 f1 = {blo(u.z), bhi(u.z), blo(u.w), bhi(u.w)};
            *(float4*)&xt[n][cc * 8] = f0;
            *(float4*)&xt[n][cc * 8 + 4] = f1;
        }
        __syncthreads();
        int n = tid >> 3, t = tid & 7;
        float acc = 0.f;
        for (int k = 0; k < 128; k += 4) {
            float4 xv = *(const float4*)&xt[n][k];
            float4 pv = *(const float4*)&ph[t][k];
            acc += xv.x * pv.x + xv.y * pv.y + xv.z * pv.z + xv.w * pv.w;
        }
        sc[t][n0 + n] = acc;
        __syncthreads();
    }
    for (int t = 0; t < TTOK; ++t) {
        float m = -1e30f;
        for (int n = tid; n < NPG; n += 256) m = fmaxf(m, sc[t][n]);
        for (int off = 32; off; off >>= 1) m = fmaxf(m, __shfl_down(m, off));
        if ((tid & 63) == 0) red[tid >> 6] = m;
        __syncthreads();
        m = fmaxf(fmaxf(red[0], red[1]), fmaxf(red[2], red[3]));
        float s = 0.f;
        for (int n = tid; n < NPG; n += 256) {
            float e = __expf(sc[t][n] - m);
            sc[t][n] = e;
            s += e;
        }
        for (int off = 32; off; off >>= 1) s += __shfl_down(s, off);
        if ((tid & 63) == 0) red[4 + (tid >> 6)] = s;
        __syncthreads();
        s = red[4] + red[5] + red[6] + red[7];
        float inv = 1.f / s;
        for (int n = tid; n < NPG; n += 256) sc[t][n] *= inv;
        __syncthreads();
    }
    {
        int t = tid >> 5, c4 = (tid & 31) * 4;
        float4 acc = {0.f, 0.f, 0.f, 0.f};
        for (int n = 0; n < NPG; ++n) {
            float w = sc[t][n];
            ushort4 v = *(const ushort4*)(xg + (size_t)n * HDIM + c4);
            acc.x += w * bf2f(v.x); acc.y += w * bf2f(v.y);
            acc.z += w * bf2f(v.z); acc.w += w * bf2f(v.w);
        }
        *(float4*)&rr[t][c4] = acc;
    }
    __syncthreads();
    {
        int t = tid >> 5, d = tid & 31;
        float acc = qkv_b[256 + h * 32 + d];
        for (int c = 0; c < 128; ++c)
            acc += rr[t][c] * qkv_w[c * 384 + 256 + h * 32 + d];
        O[((size_t)b * TTOK + t) * HDIM + h * 32 + d] = acc;
    }
}

// ================= mamba: one block per graph; GF[b][:] = mean_t output =================
__global__ __launch_bounds__(256) void mamba_kernel(const float* __restrict__ TOKp,
    const float* __restrict__ in_w, const float* __restrict__ conv_w,
    const float* __restrict__ conv_b, const float* __restrict__ x_w,
    const float* __restrict__ dt_w, const float* __restrict__ dt_b,
    const float* __restrict__ A_log, const float* __restrict__ Dp,
    const float* __restrict__ out_w, const float* __restrict__ norm_w,
    const float* __restrict__ normf_w, float* __restrict__ GF)
{
    constexpr int I = 256, S = 16;
    __shared__ float tok[TTOK][HDIM];
    __shared__ float hn[TTOK][HDIM];
    __shared__ float uu[TTOK][I];
    __shared__ float gg[TTOK][I];
    __shared__ float dtl[TTOK][I];
    __shared__ float ssm[TTOK][40];
    __shared__ float yy[TTOK][I];
    int b = blockIdx.x, tid = threadIdx.x;
    for (int i = tid; i < TTOK * HDIM; i += 256) tok[i >> 7][i & 127] = TOKp[(size_t)b * TTOK * HDIM + i];
    __syncthreads();
    {
        int t = tid >> 5, lane = tid & 31;
        float s = 0.f;
        for (int c = lane; c < HDIM; c += 32) { float v = tok[t][c]; s += v * v; }
        for (int off = 16; off; off >>= 1) s += __shfl_down(s, off, 32);
        s = __shfl(s, 0, 32);
        float r = rsqrtf(s / HDIM + 1e-5f);
        for (int c = lane; c < HDIM; c += 32) hn[t][c] = tok[t][c] * r * norm_w[c];
    }
    __syncthreads();
    for (int it = 0; it < 16; ++it) {
        int idx = it * 256 + tid;
        int t = idx >> 9, j = idx & 511;
        float acc = 0.f;
        for (int c = 0; c < 128; ++c) acc += hn[t][c] * in_w[c * 512 + j];
        if (j < 256) uu[t][j] = acc; else gg[t][j - 256] = acc;
    }
    __syncthreads();
    {
        int i = tid;
        float cw0 = conv_w[i * 4 + 0], cw1 = conv_w[i * 4 + 1];
        float cw2 = conv_w[i * 4 + 2], cw3 = conv_w[i * 4 + 3];
        float cb = conv_b[i];
        float uv[TTOK];
        for (int t = 0; t < TTOK; ++t) uv[t] = uu[t][i];
        for (int t = 0; t < TTOK; ++t) {
            float a = cw3 * uv[t] + cb;
            if (t >= 1) a += cw2 * uv[t - 1];
            if (t >= 2) a += cw1 * uv[t - 2];
            if (t >= 3) a += cw0 * uv[t - 3];
            float sg = 1.f / (1.f + __expf(-a));
            uu[t][i] = a * sg;
        }
    }
    __syncthreads();
    for (int idx = tid; idx < TTOK * 40; idx += 256) {
        int t = idx / 40, j = idx % 40;
        float acc = 0.f;
        for (int c = 0; c < 256; ++c) acc += uu[t][c] * x_w[c * 40 + j];
        ssm[t][j] = acc;
    }
    __syncthreads();
    for (int idx = tid; idx < TTOK * I; idx += 256) {
        int t = idx >> 8, i = idx & 255;
        float acc = dt_b[i];
        for (int r = 0; r < 8; ++r) acc += ssm[t][r] * dt_w[r * 256 + i];
        dtl[t][i] = (acc > 20.f) ? acc : log1pf(__expf(acc));
    }
    __syncthreads();
    {
        int i = tid;
        float a[S], st[S];
        for (int s = 0; s < S; ++s) { a[s] = -__expf(A_log[i * S + s]); st[s] = 0.f; }
        float Di = Dp[i];
        for (int t = 0; t < TTOK; ++t) {
            float d = dtl[t][i];
            float ut = uu[t][i];
            float y = 0.f;
            for (int s = 0; s < S; ++s) {
                float dA = __expf(d * a[s]);
                st[s] = dA * st[s] + d * ssm[t][8 + s] * ut;
                y += st[s] * ssm[t][24 + s];
            }
            y += ut * Di;
            float g = gg[t][i];
            float sg = 1.f / (1.f + __expf(-g));
            yy[t][i] = y * g * sg;
        }
    }
    __syncthreads();
    for (int idx = tid; idx < TTOK * HDIM; idx += 256) {
        int t = idx >> 7, c = idx & 127;
        float acc = tok[t][c];
        for (int i = 0; i < 256; ++i) acc += yy[t][i] * out_w[i * 128 + c];
        hn[t][c] = acc;
    }
    __syncthreads();
    {
        int t = tid >> 5, lane = tid & 31;
        float s = 0.f;
        for (int c = lane; c < HDIM; c += 32) { float v = hn[t][c]; s += v * v; }
        for (int off = 16; off; off >>= 1) s += __shfl_down(s, off, 32);
        s = __shfl(s, 0, 32);
        float r = rsqrtf(s / HDIM + 1e-5f);
        for (int c = lane; c < HDIM; c += 32) hn[t][c] = hn[t][c] * r * normf_w[c];
    }
    __syncthreads();
    for (int c = tid; c < HDIM; c += 256) {
        float s = 0.f;
        for (int t = 0; t < TTOK; ++t) s += hn[t][c];
        GF[(size_t)b * HDIM + c] = s * (1.f / TTOK);
    }
}

// ================= final GIN + segment_sum: partial sums, 32 blocks/graph, bf16 X =================
__global__ __launch_bounds__(256) void final_partial_kernel(const ushort* __restrict__ X,
    const int* __restrict__ ssrc, const int* __restrict__ starts,
    float* __restrict__ PS)
{
    __shared__ float part[16][HDIM];
    int b = blockIdx.x >> 5;        // graph
    int j = blockIdx.x & 31;        // slice within graph
    int tid = threadIdx.x;
    int g = tid >> 4, lane = tid & 15;   // 16 groups x 16 lanes
    const int c = lane * 8;
    float a0 = 0.f, a1 = 0.f, a2 = 0.f, a3 = 0.f;
    float a4 = 0.f, a5 = 0.f, a6 = 0.f, a7 = 0.f;
    {
        int nb = j * 32 + g * 2;
        for (int n = nb; n < nb + 2; ++n) {
            uint4 u = *((const uint4*)(X + ((size_t)b * NPG + n) * HDIM) + lane);
            a0 += blo(u.x); a1 += bhi(u.x); a2 += blo(u.y); a3 += bhi(u.y);
            a4 += blo(u.z); a5 += bhi(u.z); a6 += blo(u.w); a7 += bhi(u.w);
        }
    }
    {
        int e0 = starts[b * NPG], e1 = starts[(b + 1) * NPG];
        int tot = e1 - e0;
        int gi = j * 16 + g;                     // 0..511
        int per = (tot + 511) >> 9;
        int cs = e0 + gi * per;
        int ce = min(cs + per, e1);
        for (int j0 = cs; j0 < ce; j0 += 16) {
            int myid = (j0 + lane < ce) ? ssrc[j0 + lane] : 0;
            int m = min(16, ce - j0);
            for (int jj = 0; jj < m; ++jj) {
                int sa = __shfl(myid, jj, 16);
                uint4 u = *((const uint4*)(X + (size_t)sa * HDIM) + lane);
                a0 += blo(u.x); a1 += bhi(u.x); a2 += blo(u.y); a3 += bhi(u.y);
                a4 += blo(u.z); a5 += bhi(u.z); a6 += blo(u.w); a7 += bhi(u.w);
            }
        }
    }
    part[g][c + 0] = a0; part[g][c + 1] = a1; part[g][c + 2] = a2; part[g][c + 3] = a3;
    part[g][c + 4] = a4; part[g][c + 5] = a5; part[g][c + 6] = a6; part[g][c + 7] = a7;
    __syncthreads();
    if (tid < HDIM) {
        float s = 0.f;
        for (int gg = 0; gg < 16; ++gg) s += part[gg][tid];
        atomicAdd(&PS[(size_t)b * HDIM + tid], s);
    }
}

__global__ __launch_bounds__(128) void final_mm_kernel(const float* __restrict__ PS,
    const float* __restrict__ w_out, const float* __restrict__ b_out,
    float* __restrict__ out)
{
    __shared__ float Sm[HDIM];
    int b = blockIdx.x, tid = threadIdx.x;
    Sm[tid] = PS[(size_t)b * HDIM + tid];
    __syncthreads();
    float acc = 1024.f * b_out[tid];
    for (int k = 0; k < 128; ++k) acc += Sm[k] * w_out[k * 128 + tid];
    out[(size_t)b * HDIM + tid] = acc;
}

extern "C" void kernel_launch(void* const* d_in, const int* in_sizes, int n_in,
                              void* d_out, int out_size, void* d_ws, size_t ws_size,
                              hipStream_t stream)
{
    const int N = in_sizes[0] / HDIM;      // 131072
    const int E = in_sizes[1] / 2;         // 2097152
    const int B = N >> 10;                 // 128 graphs

    const float* x_in  = (const float*)d_in[0];
    const int*   src   = (const int*)d_in[1];
    const int*   dst   = src + E;
    const float* w_in  = (const float*)d_in[5];
    const float* b_in  = (const float*)d_in[6];
    const float* gin_w = (const float*)d_in[7];
    const float* gin_b = (const float*)d_in[8];
    const float* vt    = (const float*)d_in[9];
    const float* qkv_w = (const float*)d_in[10];
    const float* qkv_b = (const float*)d_in[11];
    const float* ao_w  = (const float*)d_in[12];
    const float* ao_b  = (const float*)d_in[13];
    const float* m_in_w   = (const float*)d_in[14];
    const float* m_conv_w = (const float*)d_in[15];
    const float* m_conv_b = (const float*)d_in[16];
    const float* m_x_w    = (const float*)d_in[17];
    const float* m_dt_w   = (const float*)d_in[18];
    const float* m_dt_b   = (const float*)d_in[19];
    const float* m_A_log  = (const float*)d_in[20];
    const float* m_D      = (const float*)d_in[21];
    const float* m_out_w  = (const float*)d_in[22];
    const float* m_norm_w = (const float*)d_in[23];
    const float* m_normf_w= (const float*)d_in[24];
    const float* w_out = (const float*)d_in[25];
    const float* b_out = (const float*)d_in[26];
    float* out = (float*)d_out;

    float* TOK = (float*)d_ws;                    // B*8*128
    float* O   = TOK + (size_t)B * TTOK * HDIM;   // B*8*128
    float* GF  = O + (size_t)B * TTOK * HDIM;     // B*128
    float* P   = GF + (size_t)B * HDIM;           // 4*8*128
    float* PS  = P + 4 * TTOK * HDIM;             // B*128
    int* count    = (int*)(PS + (size_t)B * HDIM);// N
    int* starts   = count + N;                    // N+1 (padded to N+8)
    int* cursor   = starts + N + 8;               // N
    int* blocksum = cursor + N;                   // 512
    int* blockoff = blocksum + 512;               // 512
    int* ssrc     = blockoff + 512;               // E
    ushort* XB0 = (ushort*)(ssrc + E);            // N*128 bf16
    ushort* XB1 = XB0 + (size_t)N * HDIM;         // N*128 bf16
    ushort* AGG = XB1 + (size_t)N * HDIM;         // N*128 bf16

    const int EB = (E + 255) / 256;   // 8192
    const int NB = N / 256;           // 512

    // ---- counting sort of edges by dst (once, reused by all 4 GINs) ----
    hipMemsetAsync(count, 0, (size_t)N * sizeof(int), stream);
    hist_kernel<<<EB, 256, 0, stream>>>(dst, count, E);
    reduce256_kernel<<<NB, 256, 0, stream>>>(count, blocksum);
    scan512_kernel<<<1, 512, 0, stream>>>(blocksum, blockoff);
    scan_local_kernel<<<NB, 256, 0, stream>>>(count, blockoff, starts, cursor, N);
    sort_scatter_kernel<<<EB, 256, 0, stream>>>(src, dst, cursor, ssrc, E);

    // ---- input GIN: XB1 = (x + agg(x)) @ w_in + b_in ----
    convert_kernel<<<(N * 32 + 255) / 256, 256, 0, stream>>>(x_in, XB0, N * 32);
    gather_kernel<<<N / 16, 256, 0, stream>>>(XB0, ssrc, starts, count, AGG);
    lin128b_kernel<<<N / 32, 256, 0, stream>>>(AGG, w_in, b_in, nullptr, XB1);

    ushort* Xcur = XB1;
    ushort* Xnext = XB0;
    for (int l = 0; l < 2; ++l) {
        // attention pool on Xcur -> O -> TOK -> mamba -> GF
        attn_prep_kernel<<<1, 256, 0, stream>>>(vt + (size_t)l * TTOK * HDIM,
                                                qkv_w + (size_t)l * 128 * 384,
                                                qkv_b + (size_t)l * 384, P);
        attn_main_kernel<<<B * 4, 256, 0, stream>>>(Xcur, P,
                                                    qkv_w + (size_t)l * 128 * 384,
                                                    qkv_b + (size_t)l * 384, O);
        lin128_kernel<<<(B * TTOK) / 32, 256, 0, stream>>>(O, ao_w + (size_t)l * 128 * 128,
                                                           ao_b + (size_t)l * 128, TOK);
        mamba_kernel<<<B, 256, 0, stream>>>(TOK, m_in_w, m_conv_w, m_conv_b, m_x_w,
                                            m_dt_w, m_dt_b, m_A_log, m_D, m_out_w,
                                            m_norm_w, m_normf_w, GF);
        // GIN: AGG = Xcur + agg(Xcur); Xnext = AGG @ gin_w + gin_b + GF[batch]
        gather_kernel<<<N / 16, 256, 0, stream>>>(Xcur, ssrc, starts, count, AGG);
        lin128b_kernel<<<N / 32, 256, 0, stream>>>(AGG, gin_w + (size_t)l * 128 * 128,
                                                   gin_b + (size_t)l * 128, GF, Xnext);
        ushort* t = Xcur; Xcur = Xnext; Xnext = t;
    }

    // ---- final GIN + segment_sum: partials + tiny matmul ----
    hipMemsetAsync(PS, 0, (size_t)B * HDIM * sizeof(float), stream);
    final_partial_kernel<<<B * 32, 256, 0, stream>>>(Xcur, ssrc, starts, PS);
    final_mm_kernel<<<B, 128, 0, stream>>>(PS, w_out, b_out, out);

    (void)n_in; (void)out_size; (void)ws_size;
}

// Round 6
// 1387.976 us; speedup vs baseline: 1.3522x; 1.1446x over previous
//
#include <hip/hip_runtime.h>

#define HDIM 128
#define TTOK 8
#define NPG 1024

typedef unsigned short ushort;
typedef unsigned int uint;
typedef __attribute__((ext_vector_type(8))) short short8;
typedef __attribute__((ext_vector_type(4))) float f32x4;

__device__ __forceinline__ float bf2f(ushort u) {
    return __uint_as_float(((unsigned int)u) << 16);
}
__device__ __forceinline__ ushort f2bf(float f) {
    unsigned int x = __float_as_uint(f);
    return (ushort)((x + 0x7FFFu + ((x >> 16) & 1u)) >> 16);
}
__device__ __forceinline__ float blo(uint u) { return __uint_as_float(u << 16); }
__device__ __forceinline__ float bhi(uint u) { return __uint_as_float(u & 0xFFFF0000u); }
__device__ __forceinline__ uint pk(float a, float b) {
    return (uint)f2bf(a) | ((uint)f2bf(b) << 16);
}

// ================= counting sort of edges by dst =================

__global__ __launch_bounds__(256) void hist_kernel(const int* __restrict__ dst,
                                                   int* __restrict__ count, int E)
{
    int e = blockIdx.x * 256 + threadIdx.x;
    if (e < E) atomicAdd(&count[dst[e]], 1);
}

__global__ __launch_bounds__(256) void reduce256_kernel(const int* __restrict__ count,
                                                        int* __restrict__ blocksum)
{
    __shared__ int sm[256];
    int tid = threadIdx.x;
    sm[tid] = count[blockIdx.x * 256 + tid];
    __syncthreads();
    for (int s = 128; s; s >>= 1) {
        if (tid < s) sm[tid] += sm[tid + s];
        __syncthreads();
    }
    if (tid == 0) blocksum[blockIdx.x] = sm[0];
}

__global__ __launch_bounds__(512) void scan512_kernel(const int* __restrict__ blocksum,
                                                      int* __restrict__ blockoff)
{
    __shared__ int tmp[512];
    int tid = threadIdx.x;
    int v = blocksum[tid];
    tmp[tid] = v;
    __syncthreads();
    for (int off = 1; off < 512; off <<= 1) {
        int t = (tid >= off) ? tmp[tid - off] : 0;
        __syncthreads();
        tmp[tid] += t;
        __syncthreads();
    }
    blockoff[tid] = tmp[tid] - v;  // exclusive
}

__global__ __launch_bounds__(256) void scan_local_kernel(const int* __restrict__ count,
    const int* __restrict__ blockoff, int* __restrict__ starts,
    int* __restrict__ cursor, int N)
{
    __shared__ int tmp[256];
    int tid = threadIdx.x;
    int i = blockIdx.x * 256 + tid;
    int v = count[i];
    tmp[tid] = v;
    __syncthreads();
    for (int off = 1; off < 256; off <<= 1) {
        int t = (tid >= off) ? tmp[tid - off] : 0;
        __syncthreads();
        tmp[tid] += t;
        __syncthreads();
    }
    int excl = tmp[tid] - v + blockoff[blockIdx.x];
    starts[i] = excl;
    cursor[i] = excl;
    if (i == N - 1) starts[N] = excl + v;  // == E
}

__global__ __launch_bounds__(256) void sort_scatter_kernel(const int* __restrict__ src,
    const int* __restrict__ dst, int* __restrict__ cursor,
    int* __restrict__ ssrc, int E)
{
    int e = blockIdx.x * 256 + threadIdx.x;
    if (e >= E) return;
    int pos = atomicAdd(&cursor[dst[e]], 1);
    ssrc[pos] = src[e];
}

// ================= f32 -> bf16 convert =================
__global__ __launch_bounds__(256) void convert_kernel(const float* __restrict__ in,
                                                      ushort* __restrict__ outb, int n4)
{
    int i = blockIdx.x * 256 + threadIdx.x;
    if (i >= n4) return;
    float4 v = ((const float4*)in)[i];
    uint2 o;
    o.x = pk(v.x, v.y); o.y = pk(v.z, v.w);
    ((uint2*)outb)[i] = o;
}

// ================= gather: AGG[n] = x[n] + sum_{e: dst=n} x[src[e]]  (bf16 in/out) =================
// 16 nodes per block, 16 lanes per node, uint4 = 8 bf16 per lane, 4-deep load ILP.
__global__ __launch_bounds__(256) void gather_kernel(const ushort* __restrict__ XS,
    const int* __restrict__ ssrc, const int* __restrict__ starts,
    const int* __restrict__ count, ushort* __restrict__ AGG)
{
    int tid = threadIdx.x;
    int g = tid >> 4, lane = tid & 15;
    int node = blockIdx.x * 16 + g;
    uint4 sv = *((const uint4*)(XS + (size_t)node * HDIM) + lane);
    float a0 = blo(sv.x), a1 = bhi(sv.x), a2 = blo(sv.y), a3 = bhi(sv.y);
    float a4 = blo(sv.z), a5 = bhi(sv.z), a6 = blo(sv.w), a7 = bhi(sv.w);
    int s0 = starts[node], cn = count[node];
    for (int j0 = 0; j0 < cn; j0 += 16) {
        int myid = (j0 + lane < cn) ? ssrc[s0 + j0 + lane] : 0;
        int m = min(16, cn - j0);
        int j = 0;
        for (; j + 3 < m; j += 4) {
            int sa = __shfl(myid, j, 16);
            int sb = __shfl(myid, j + 1, 16);
            int sc = __shfl(myid, j + 2, 16);
            int sd = __shfl(myid, j + 3, 16);
            uint4 ua = *((const uint4*)(XS + (size_t)sa * HDIM) + lane);
            uint4 ub = *((const uint4*)(XS + (size_t)sb * HDIM) + lane);
            uint4 uc = *((const uint4*)(XS + (size_t)sc * HDIM) + lane);
            uint4 ud = *((const uint4*)(XS + (size_t)sd * HDIM) + lane);
            a0 += (blo(ua.x) + blo(ub.x)) + (blo(uc.x) + blo(ud.x));
            a1 += (bhi(ua.x) + bhi(ub.x)) + (bhi(uc.x) + bhi(ud.x));
            a2 += (blo(ua.y) + blo(ub.y)) + (blo(uc.y) + blo(ud.y));
            a3 += (bhi(ua.y) + bhi(ub.y)) + (bhi(uc.y) + bhi(ud.y));
            a4 += (blo(ua.z) + blo(ub.z)) + (blo(uc.z) + blo(ud.z));
            a5 += (bhi(ua.z) + bhi(ub.z)) + (bhi(uc.z) + bhi(ud.z));
            a6 += (blo(ua.w) + blo(ub.w)) + (blo(uc.w) + blo(ud.w));
            a7 += (bhi(ua.w) + bhi(ub.w)) + (bhi(uc.w) + bhi(ud.w));
        }
        for (; j < m; ++j) {
            int sa = __shfl(myid, j, 16);
            uint4 ua = *((const uint4*)(XS + (size_t)sa * HDIM) + lane);
            a0 += blo(ua.x); a1 += bhi(ua.x);
            a2 += blo(ua.y); a3 += bhi(ua.y);
            a4 += blo(ua.z); a5 += bhi(ua.z);
            a6 += blo(ua.w); a7 += bhi(ua.w);
        }
    }
    uint4 o;
    o.x = pk(a0, a1); o.y = pk(a2, a3); o.z = pk(a4, a5); o.w = pk(a6, a7);
    *((uint4*)(AGG + (size_t)node * HDIM) + lane) = o;
}

// ================= MFMA linear (bf16 in/out): XD = XS @ W + b [+ GF[row>>10]] =================
// 128 rows per block, 4 waves; X-tile + W^T staged in LDS bf16 with XOR-swizzled 16B chunks.
__global__ __launch_bounds__(256) void lin128_mfma_kernel(const ushort* __restrict__ XS,
    const float* __restrict__ W, const float* __restrict__ bias,
    const float* __restrict__ GF, ushort* __restrict__ XD)
{
    __shared__ ushort Xl[128 * 128];   // 32 KB  [row][k], chunk-swizzled
    __shared__ ushort Wl[128 * 128];   // 32 KB  [n][k],   chunk-swizzled (W transposed)
    int tid = threadIdx.x;
    size_t r0 = (size_t)blockIdx.x * 128;
    // stage X tile
    {
        const uint4* xs = (const uint4*)(XS + r0 * HDIM);
        uint4* xl = (uint4*)Xl;
        for (int i = tid; i < 2048; i += 256) {
            int row = i >> 4, cc = i & 15;
            xl[row * 16 + (cc ^ (row & 15))] = xs[i];
        }
    }
    // stage W transposed -> bf16: chunk (n, c) holds W[c*8+j][n], j=0..7
    {
        uint4* wl = (uint4*)Wl;
        for (int i = tid; i < 2048; i += 256) {
            int n = i & 127, c = i >> 7;   // c in 0..15
            const float* wp = W + (size_t)(c * 8) * 128 + n;
            float w0 = wp[0], w1 = wp[128], w2 = wp[256], w3 = wp[384];
            float w4 = wp[512], w5 = wp[640], w6 = wp[768], w7 = wp[896];
            uint4 u;
            u.x = pk(w0, w1); u.y = pk(w2, w3); u.z = pk(w4, w5); u.w = pk(w6, w7);
            wl[n * 16 + (c ^ (n & 15))] = u;
        }
    }
    __syncthreads();
    int wave = tid >> 6;
    int lane = tid & 63;
    int m16 = lane & 15, quad = lane >> 4;
    const short8* Xf = (const short8*)Xl;
    const short8* Wf = (const short8*)Wl;
    // A fragments: 2 row-tiles x 4 k-chunks
    short8 afr[2][4];
    #pragma unroll
    for (int rt = 0; rt < 2; ++rt)
        #pragma unroll
        for (int kc = 0; kc < 4; ++kc)
            afr[rt][kc] = Xf[(wave * 32 + rt * 16 + m16) * 16 + ((kc * 4 + quad) ^ m16)];
    int graph = (int)(r0 >> 10);
    #pragma unroll
    for (int ct = 0; ct < 8; ++ct) {
        int col = ct * 16 + m16;
        short8 bfr[4];
        #pragma unroll
        for (int kc = 0; kc < 4; ++kc)
            bfr[kc] = Wf[col * 16 + ((kc * 4 + quad) ^ m16)];
        f32x4 acc0 = {0.f, 0.f, 0.f, 0.f};
        f32x4 acc1 = {0.f, 0.f, 0.f, 0.f};
        #pragma unroll
        for (int kc = 0; kc < 4; ++kc) {
            acc0 = __builtin_amdgcn_mfma_f32_16x16x32_bf16(afr[0][kc], bfr[kc], acc0, 0, 0, 0);
            acc1 = __builtin_amdgcn_mfma_f32_16x16x32_bf16(afr[1][kc], bfr[kc], acc1, 0, 0, 0);
        }
        float add = bias[col] + (GF ? GF[(size_t)graph * HDIM + col] : 0.f);
        #pragma unroll
        for (int r = 0; r < 4; ++r) {
            XD[(r0 + wave * 32 + quad * 4 + r) * HDIM + col] = f2bf(acc0[r] + add);
            XD[(r0 + wave * 32 + 16 + quad * 4 + r) * HDIM + col] = f2bf(acc1[r] + add);
        }
    }
}

// ================= Y = X1 @ W + b (f32; attn output proj -> TOK) =================
__global__ __launch_bounds__(256) void lin128_kernel(const float* __restrict__ X1,
    const float* __restrict__ W, const float* __restrict__ bias,
    float* __restrict__ Y)
{
    __shared__ float Wl[128 * 128];
    __shared__ float xr[32][128];
    int tid = threadIdx.x;
    for (int i = tid; i < 4096; i += 256)
        ((float4*)Wl)[i] = ((const float4*)W)[i];
    size_t r0 = (size_t)blockIdx.x * 32;
    for (int i = tid; i < 32 * 32; i += 256) {
        int r = i >> 5, c4 = i & 31;
        *(float4*)&xr[r][c4 * 4] = *(const float4*)(X1 + (r0 + r) * HDIM + c4 * 4);
    }
    __syncthreads();
    int cg = tid & 31, rg = tid >> 5;
    int c0 = cg * 4, rb = rg * 4;
    float4 bv = *(const float4*)(bias + c0);
    float4 a0 = bv, a1 = bv, a2 = bv, a3 = bv;
    for (int k = 0; k < 128; ++k) {
        float4 w = *(const float4*)&Wl[k * 128 + c0];
        float x0 = xr[rb + 0][k], x1 = xr[rb + 1][k], x2 = xr[rb + 2][k], x3 = xr[rb + 3][k];
        a0.x += x0 * w.x; a0.y += x0 * w.y; a0.z += x0 * w.z; a0.w += x0 * w.w;
        a1.x += x1 * w.x; a1.y += x1 * w.y; a1.z += x1 * w.z; a1.w += x1 * w.w;
        a2.x += x2 * w.x; a2.y += x2 * w.y; a2.z += x2 * w.z; a2.w += x2 * w.w;
        a3.x += x3 * w.x; a3.y += x3 * w.y; a3.z += x3 * w.z; a3.w += x3 * w.w;
    }
    *(float4*)(Y + (r0 + rb + 0) * HDIM + c0) = a0;
    *(float4*)(Y + (r0 + rb + 1) * HDIM + c0) = a1;
    *(float4*)(Y + (r0 + rb + 2) * HDIM + c0) = a2;
    *(float4*)(Y + (r0 + rb + 3) * HDIM + c0) = a3;
}

// ================= attention prep (both layers): P[l][h][t][:] = Wk_h @ q[t,h] / sqrt(32) =================
__global__ __launch_bounds__(256) void attn_prep_kernel(const float* __restrict__ vt,
    const float* __restrict__ qkv_w, const float* __restrict__ qkv_b, float* __restrict__ P)
{
    __shared__ float vtl[TTOK][HDIM];
    __shared__ float q[TTOK][HDIM];
    int l = blockIdx.x;
    const float* vtp = vt + (size_t)l * TTOK * HDIM;
    const float* qw = qkv_w + (size_t)l * 128 * 384;
    const float* qb = qkv_b + (size_t)l * 384;
    float* Pp = P + (size_t)l * 4 * TTOK * HDIM;
    int tid = threadIdx.x;
    for (int i = tid; i < TTOK * HDIM; i += 256) vtl[i >> 7][i & 127] = vtp[i];
    __syncthreads();
    for (int i = tid; i < TTOK * HDIM; i += 256) {
        int t = i >> 7, j = i & 127;
        float acc = qb[j];
        for (int c = 0; c < 128; ++c) acc += vtl[t][c] * qw[c * 384 + j];
        q[t][j] = acc;
    }
    __syncthreads();
    const float scale = 0.17677669529663687f; // 1/sqrt(32)
    for (int i = tid; i < 4 * TTOK * HDIM; i += 256) {
        int h = i >> 10, t = (i >> 7) & 7, cc = i & 127;
        float acc = 0.f;
        for (int d = 0; d < 32; ++d)
            acc += qw[cc * 384 + 128 + h * 32 + d] * q[t][h * 32 + d];
        Pp[i] = acc * scale;
    }
}

// ================= fused attention per (graph, head), bf16 X =================
__global__ __launch_bounds__(256) void attn_main_kernel(const ushort* __restrict__ X,
    const float* __restrict__ P, const float* __restrict__ qkv_w,
    const float* __restrict__ qkv_b, float* __restrict__ O)
{
    __shared__ float sc[TTOK][NPG];   // 32 KB scores
    __shared__ float ph[TTOK][132];
    __shared__ float xt[32][132];
    __shared__ float rr[TTOK][HDIM];
    __shared__ float red[16];
    int b = blockIdx.x >> 2;
    int h = blockIdx.x & 3;
    int tid = threadIdx.x;
    for (int i = tid; i < TTOK * HDIM; i += 256) ph[i >> 7][i & 127] = P[h * 1024 + i];
    __syncthreads();
    const ushort* xg = X + (size_t)b * NPG * HDIM;
    for (int n0 = 0; n0 < NPG; n0 += 32) {
        for (int i = tid; i < 32 * 16; i += 256) {
            int n = i >> 4, cc = i & 15;
            uint4 u = *((const uint4*)(xg + (size_t)(n0 + n) * HDIM) + cc);
            float4 f0 = {blo(u.x), bhi(u.x), blo(u.y), bhi(u.y)};
            float4 f1 = {blo(u.z), bhi(u.z), blo(u.w), bhi(u.w)};
            *(float4*)&xt[n][cc * 8] = f0;
            *(float4*)&xt[n][cc * 8 + 4] = f1;
        }
        __syncthreads();
        int n = tid >> 3, t = tid & 7;
        float acc = 0.f;
        for (int k = 0; k < 128; k += 4) {
            float4 xv = *(const float4*)&xt[n][k];
            float4 pv = *(const float4*)&ph[t][k];
            acc += xv.x * pv.x + xv.y * pv.y + xv.z * pv.z + xv.w * pv.w;
        }
        sc[t][n0 + n] = acc;
        __syncthreads();
    }
    for (int t = 0; t < TTOK; ++t) {
        float m = -1e30f;
        for (int n = tid; n < NPG; n += 256) m = fmaxf(m, sc[t][n]);
        for (int off = 32; off; off >>= 1) m = fmaxf(m, __shfl_down(m, off));
        if ((tid & 63) == 0) red[tid >> 6] = m;
        __syncthreads();
        m = fmaxf(fmaxf(red[0], red[1]), fmaxf(red[2], red[3]));
        float s = 0.f;
        for (int n = tid; n < NPG; n += 256) {
            float e = __expf(sc[t][n] - m);
            sc[t][n] = e;
            s += e;
        }
        for (int off = 32; off; off >>= 1) s += __shfl_down(s, off);
        if ((tid & 63) == 0) red[4 + (tid >> 6)] = s;
        __syncthreads();
        s = red[4] + red[5] + red[6] + red[7];
        float inv = 1.f / s;
        for (int n = tid; n < NPG; n += 256) sc[t][n] *= inv;
        __syncthreads();
    }
    {
        int t = tid >> 5, c4 = (tid & 31) * 4;
        float4 acc = {0.f, 0.f, 0.f, 0.f};
        for (int n = 0; n < NPG; ++n) {
            float w = sc[t][n];
            ushort4 v = *(const ushort4*)(xg + (size_t)n * HDIM + c4);
            acc.x += w * bf2f(v.x); acc.y += w * bf2f(v.y);
            acc.z += w * bf2f(v.z); acc.w += w * bf2f(v.w);
        }
        *(float4*)&rr[t][c4] = acc;
    }
    __syncthreads();
    {
        int t = tid >> 5, d = tid & 31;
        float acc = qkv_b[256 + h * 32 + d];
        for (int c = 0; c < 128; ++c)
            acc += rr[t][c] * qkv_w[c * 384 + 256 + h * 32 + d];
        O[((size_t)b * TTOK + t) * HDIM + h * 32 + d] = acc;
    }
}

// ================= mamba: one block per graph; GF[b][:] = mean_t output =================
__global__ __launch_bounds__(256) void mamba_kernel(const float* __restrict__ TOKp,
    const float* __restrict__ in_w, const float* __restrict__ conv_w,
    const float* __restrict__ conv_b, const float* __restrict__ x_w,
    const float* __restrict__ dt_w, const float* __restrict__ dt_b,
    const float* __restrict__ A_log, const float* __restrict__ Dp,
    const float* __restrict__ out_w, const float* __restrict__ norm_w,
    const float* __restrict__ normf_w, float* __restrict__ GF)
{
    constexpr int I = 256, S = 16;
    __shared__ float tok[TTOK][HDIM];
    __shared__ float hn[TTOK][HDIM];
    __shared__ float uu[TTOK][I];
    __shared__ float gg[TTOK][I];
    __shared__ float dtl[TTOK][I];
    __shared__ float ssm[TTOK][40];
    __shared__ float yy[TTOK][I];
    int b = blockIdx.x, tid = threadIdx.x;
    for (int i = tid; i < TTOK * HDIM; i += 256) tok[i >> 7][i & 127] = TOKp[(size_t)b * TTOK * HDIM + i];
    __syncthreads();
    {
        int t = tid >> 5, lane = tid & 31;
        float s = 0.f;
        for (int c = lane; c < HDIM; c += 32) { float v = tok[t][c]; s += v * v; }
        for (int off = 16; off; off >>= 1) s += __shfl_down(s, off, 32);
        s = __shfl(s, 0, 32);
        float r = rsqrtf(s / HDIM + 1e-5f);
        for (int c = lane; c < HDIM; c += 32) hn[t][c] = tok[t][c] * r * norm_w[c];
    }
    __syncthreads();
    for (int it = 0; it < 16; ++it) {
        int idx = it * 256 + tid;
        int t = idx >> 9, j = idx & 511;
        float acc = 0.f;
        for (int c = 0; c < 128; ++c) acc += hn[t][c] * in_w[c * 512 + j];
        if (j < 256) uu[t][j] = acc; else gg[t][j - 256] = acc;
    }
    __syncthreads();
    {
        int i = tid;
        float cw0 = conv_w[i * 4 + 0], cw1 = conv_w[i * 4 + 1];
        float cw2 = conv_w[i * 4 + 2], cw3 = conv_w[i * 4 + 3];
        float cb = conv_b[i];
        float uv[TTOK];
        for (int t = 0; t < TTOK; ++t) uv[t] = uu[t][i];
        for (int t = 0; t < TTOK; ++t) {
            float a = cw3 * uv[t] + cb;
            if (t >= 1) a += cw2 * uv[t - 1];
            if (t >= 2) a += cw1 * uv[t - 2];
            if (t >= 3) a += cw0 * uv[t - 3];
            float sg = 1.f / (1.f + __expf(-a));
            uu[t][i] = a * sg;
        }
    }
    __syncthreads();
    for (int idx = tid; idx < TTOK * 40; idx += 256) {
        int t = idx / 40, j = idx % 40;
        float acc = 0.f;
        for (int c = 0; c < 256; ++c) acc += uu[t][c] * x_w[c * 40 + j];
        ssm[t][j] = acc;
    }
    __syncthreads();
    for (int idx = tid; idx < TTOK * I; idx += 256) {
        int t = idx >> 8, i = idx & 255;
        float acc = dt_b[i];
        for (int r = 0; r < 8; ++r) acc += ssm[t][r] * dt_w[r * 256 + i];
        dtl[t][i] = (acc > 20.f) ? acc : log1pf(__expf(acc));
    }
    __syncthreads();
    {
        int i = tid;
        float a[S], st[S];
        for (int s = 0; s < S; ++s) { a[s] = -__expf(A_log[i * S + s]); st[s] = 0.f; }
        float Di = Dp[i];
        for (int t = 0; t < TTOK; ++t) {
            float d = dtl[t][i];
            float ut = uu[t][i];
            float y = 0.f;
            for (int s = 0; s < S; ++s) {
                float dA = __expf(d * a[s]);
                st[s] = dA * st[s] + d * ssm[t][8 + s] * ut;
                y += st[s] * ssm[t][24 + s];
            }
            y += ut * Di;
            float g = gg[t][i];
            float sg = 1.f / (1.f + __expf(-g));
            yy[t][i] = y * g * sg;
        }
    }
    __syncthreads();
    for (int idx = tid; idx < TTOK * HDIM; idx += 256) {
        int t = idx >> 7, c = idx & 127;
        float acc = tok[t][c];
        for (int i = 0; i < 256; ++i) acc += yy[t][i] * out_w[i * 128 + c];
        hn[t][c] = acc;
    }
    __syncthreads();
    {
        int t = tid >> 5, lane = tid & 31;
        float s = 0.f;
        for (int c = lane; c < HDIM; c += 32) { float v = hn[t][c]; s += v * v; }
        for (int off = 16; off; off >>= 1) s += __shfl_down(s, off, 32);
        s = __shfl(s, 0, 32);
        float r = rsqrtf(s / HDIM + 1e-5f);
        for (int c = lane; c < HDIM; c += 32) hn[t][c] = hn[t][c] * r * normf_w[c];
    }
    __syncthreads();
    for (int c = tid; c < HDIM; c += 256) {
        float s = 0.f;
        for (int t = 0; t < TTOK; ++t) s += hn[t][c];
        GF[(size_t)b * HDIM + c] = s * (1.f / TTOK);
    }
}

// ================= final GIN + segment_sum: partial sums, 32 blocks/graph, bf16 X =================
__global__ __launch_bounds__(256) void final_partial_kernel(const ushort* __restrict__ X,
    const int* __restrict__ ssrc, const int* __restrict__ starts,
    float* __restrict__ PS)
{
    __shared__ float part[16][HDIM];
    int b = blockIdx.x >> 5;        // graph
    int j = blockIdx.x & 31;        // slice within graph
    int tid = threadIdx.x;
    int g = tid >> 4, lane = tid & 15;   // 16 groups x 16 lanes
    const int c = lane * 8;
    float a0 = 0.f, a1 = 0.f, a2 = 0.f, a3 = 0.f;
    float a4 = 0.f, a5 = 0.f, a6 = 0.f, a7 = 0.f;
    {
        int nb = j * 32 + g * 2;
        for (int n = nb; n < nb + 2; ++n) {
            uint4 u = *((const uint4*)(X + ((size_t)b * NPG + n) * HDIM) + lane);
            a0 += blo(u.x); a1 += bhi(u.x); a2 += blo(u.y); a3 += bhi(u.y);
            a4 += blo(u.z); a5 += bhi(u.z); a6 += blo(u.w); a7 += bhi(u.w);
        }
    }
    {
        int e0 = starts[b * NPG], e1 = starts[(b + 1) * NPG];
        int tot = e1 - e0;
        int gi = j * 16 + g;                     // 0..511
        int per = (tot + 511) >> 9;
        int cs = e0 + gi * per;
        int ce = min(cs + per, e1);
        for (int j0 = cs; j0 < ce; j0 += 16) {
            int myid = (j0 + lane < ce) ? ssrc[j0 + lane] : 0;
            int m = min(16, ce - j0);
            int jj = 0;
            for (; jj + 3 < m; jj += 4) {
                int sa = __shfl(myid, jj, 16);
                int sb = __shfl(myid, jj + 1, 16);
                int sc = __shfl(myid, jj + 2, 16);
                int sd = __shfl(myid, jj + 3, 16);
                uint4 ua = *((const uint4*)(X + (size_t)sa * HDIM) + lane);
                uint4 ub = *((const uint4*)(X + (size_t)sb * HDIM) + lane);
                uint4 uc = *((const uint4*)(X + (size_t)sc * HDIM) + lane);
                uint4 ud = *((const uint4*)(X + (size_t)sd * HDIM) + lane);
                a0 += (blo(ua.x) + blo(ub.x)) + (blo(uc.x) + blo(ud.x));
                a1 += (bhi(ua.x) + bhi(ub.x)) + (bhi(uc.x) + bhi(ud.x));
                a2 += (blo(ua.y) + blo(ub.y)) + (blo(uc.y) + blo(ud.y));
                a3 += (bhi(ua.y) + bhi(ub.y)) + (bhi(uc.y) + bhi(ud.y));
                a4 += (blo(ua.z) + blo(ub.z)) + (blo(uc.z) + blo(ud.z));
                a5 += (bhi(ua.z) + bhi(ub.z)) + (bhi(uc.z) + bhi(ud.z));
                a6 += (blo(ua.w) + blo(ub.w)) + (blo(uc.w) + blo(ud.w));
                a7 += (bhi(ua.w) + bhi(ub.w)) + (bhi(uc.w) + bhi(ud.w));
            }
            for (; jj < m; ++jj) {
                int sa = __shfl(myid, jj, 16);
                uint4 u = *((const uint4*)(X + (size_t)sa * HDIM) + lane);
                a0 += blo(u.x); a1 += bhi(u.x); a2 += blo(u.y); a3 += bhi(u.y);
                a4 += blo(u.z); a5 += bhi(u.z); a6 += blo(u.w); a7 += bhi(u.w);
            }
        }
    }
    part[g][c + 0] = a0; part[g][c + 1] = a1; part[g][c + 2] = a2; part[g][c + 3] = a3;
    part[g][c + 4] = a4; part[g][c + 5] = a5; part[g][c + 6] = a6; part[g][c + 7] = a7;
    __syncthreads();
    if (tid < HDIM) {
        float s = 0.f;
        for (int gg = 0; gg < 16; ++gg) s += part[gg][tid];
        atomicAdd(&PS[(size_t)b * HDIM + tid], s);
    }
}

__global__ __launch_bounds__(128) void final_mm_kernel(const float* __restrict__ PS,
    const float* __restrict__ w_out, const float* __restrict__ b_out,
    float* __restrict__ out)
{
    __shared__ float Sm[HDIM];
    int b = blockIdx.x, tid = threadIdx.x;
    Sm[tid] = PS[(size_t)b * HDIM + tid];
    __syncthreads();
    float acc = 1024.f * b_out[tid];
    for (int k = 0; k < 128; ++k) acc += Sm[k] * w_out[k * 128 + tid];
    out[(size_t)b * HDIM + tid] = acc;
}

extern "C" void kernel_launch(void* const* d_in, const int* in_sizes, int n_in,
                              void* d_out, int out_size, void* d_ws, size_t ws_size,
                              hipStream_t stream)
{
    const int N = in_sizes[0] / HDIM;      // 131072
    const int E = in_sizes[1] / 2;         // 2097152
    const int B = N >> 10;                 // 128 graphs

    const float* x_in  = (const float*)d_in[0];
    const int*   src   = (const int*)d_in[1];
    const int*   dst   = src + E;
    const float* w_in  = (const float*)d_in[5];
    const float* b_in  = (const float*)d_in[6];
    const float* gin_w = (const float*)d_in[7];
    const float* gin_b = (const float*)d_in[8];
    const float* vt    = (const float*)d_in[9];
    const float* qkv_w = (const float*)d_in[10];
    const float* qkv_b = (const float*)d_in[11];
    const float* ao_w  = (const float*)d_in[12];
    const float* ao_b  = (const float*)d_in[13];
    const float* m_in_w   = (const float*)d_in[14];
    const float* m_conv_w = (const float*)d_in[15];
    const float* m_conv_b = (const float*)d_in[16];
    const float* m_x_w    = (const float*)d_in[17];
    const float* m_dt_w   = (const float*)d_in[18];
    const float* m_dt_b   = (const float*)d_in[19];
    const float* m_A_log  = (const float*)d_in[20];
    const float* m_D      = (const float*)d_in[21];
    const float* m_out_w  = (const float*)d_in[22];
    const float* m_norm_w = (const float*)d_in[23];
    const float* m_normf_w= (const float*)d_in[24];
    const float* w_out = (const float*)d_in[25];
    const float* b_out = (const float*)d_in[26];
    float* out = (float*)d_out;

    float* TOK = (float*)d_ws;                    // B*8*128
    float* O   = TOK + (size_t)B * TTOK * HDIM;   // B*8*128
    float* GF  = O + (size_t)B * TTOK * HDIM;     // B*128
    float* P   = GF + (size_t)B * HDIM;           // 2*4*8*128
    float* PS  = P + 2 * 4 * TTOK * HDIM;         // B*128
    int* count    = (int*)(PS + (size_t)B * HDIM);// N
    int* starts   = count + N;                    // N+1 (padded to N+8)
    int* cursor   = starts + N + 8;               // N
    int* blocksum = cursor + N;                   // 512
    int* blockoff = blocksum + 512;               // 512
    int* ssrc     = blockoff + 512;               // E
    ushort* XB0 = (ushort*)(ssrc + E);            // N*128 bf16
    ushort* XB1 = XB0 + (size_t)N * HDIM;         // N*128 bf16
    ushort* AGG = XB1 + (size_t)N * HDIM;         // N*128 bf16

    const int EB = (E + 255) / 256;   // 8192
    const int NB = N / 256;           // 512

    // ---- counting sort of edges by dst (once, reused by all 4 GINs) ----
    hipMemsetAsync(count, 0, (size_t)N * sizeof(int), stream);
    hist_kernel<<<EB, 256, 0, stream>>>(dst, count, E);
    reduce256_kernel<<<NB, 256, 0, stream>>>(count, blocksum);
    scan512_kernel<<<1, 512, 0, stream>>>(blocksum, blockoff);
    scan_local_kernel<<<NB, 256, 0, stream>>>(count, blockoff, starts, cursor, N);
    sort_scatter_kernel<<<EB, 256, 0, stream>>>(src, dst, cursor, ssrc, E);

    // ---- attention prep for both layers (independent of X) ----
    attn_prep_kernel<<<2, 256, 0, stream>>>(vt, qkv_w, qkv_b, P);

    // ---- input GIN: XB1 = (x + agg(x)) @ w_in + b_in ----
    convert_kernel<<<(N * 32 + 255) / 256, 256, 0, stream>>>(x_in, XB0, N * 32);
    gather_kernel<<<N / 16, 256, 0, stream>>>(XB0, ssrc, starts, count, AGG);
    lin128_mfma_kernel<<<N / 128, 256, 0, stream>>>(AGG, w_in, b_in, nullptr, XB1);

    ushort* Xcur = XB1;
    ushort* Xnext = XB0;
    for (int l = 0; l < 2; ++l) {
        // attention pool on Xcur -> O -> TOK -> mamba -> GF
        attn_main_kernel<<<B * 4, 256, 0, stream>>>(Xcur, P + (size_t)l * 4 * TTOK * HDIM,
                                                    qkv_w + (size_t)l * 128 * 384,
                                                    qkv_b + (size_t)l * 384, O);
        lin128_kernel<<<(B * TTOK) / 32, 256, 0, stream>>>(O, ao_w + (size_t)l * 128 * 128,
                                                           ao_b + (size_t)l * 128, TOK);
        mamba_kernel<<<B, 256, 0, stream>>>(TOK, m_in_w, m_conv_w, m_conv_b, m_x_w,
                                            m_dt_w, m_dt_b, m_A_log, m_D, m_out_w,
                                            m_norm_w, m_normf_w, GF);
        // GIN: AGG = Xcur + agg(Xcur); Xnext = AGG @ gin_w + gin_b + GF[batch]
        gather_kernel<<<N / 16, 256, 0, stream>>>(Xcur, ssrc, starts, count, AGG);
        lin128_mfma_kernel<<<N / 128, 256, 0, stream>>>(AGG, gin_w + (size_t)l * 128 * 128,
                                                        gin_b + (size_t)l * 128, GF, Xnext);
        ushort* t = Xcur; Xcur = Xnext; Xnext = t;
    }

    // ---- final GIN + segment_sum: partials + tiny matmul ----
    hipMemsetAsync(PS, 0, (size_t)B * HDIM * sizeof(float), stream);
    final_partial_kernel<<<B * 32, 256, 0, stream>>>(Xcur, ssrc, starts, PS);
    final_mm_kernel<<<B, 128, 0, stream>>>(PS, w_out, b_out, out);

    (void)n_in; (void)out_size; (void)ws_size;
}